// Round 1
// baseline (341.287 us; speedup 1.0000x reference)
//
#include <hip/hip_runtime.h>
#include <hip/hip_bf16.h>
#include <math.h>

// Problem constants (from reference):
//   B=8, C=512, H=W=64 -> HW=4096, L=HW, Td=512, N_HEADS=8 (irrelevant: KV len = 1)
// KEY INSIGHT: kv sequence length is 1 -> softmax over singleton axis == 1.0
// -> attention output == v broadcast over all L positions -> rgb_t/dep_t are
// per-(b,c) constants; Q projection and the big GEMMs are dead code. Only the
// two losses read the big tensors, and fused is a per-(b,c) value broadcast.

#define BB 8
#define CC 512
#define HWSZ 4096
#define TOTAL (BB * CC * HWSZ)   // 16777216

// Generic batched mat-vec: y[b, o] = W[o, :K] . x[b, :K] + bias[o]
// One wave (64 lanes) per output o, accumulating all 8 batches at once.
// gridDim.y selects parameter set 0 or 1 (to pair rgb/dep stages in 1 launch).
// zero_target: if non-null, block (0,0) thread 0 zeroes 3 accumulator slots.
__global__ __launch_bounds__(256) void k_mv(
    const float* __restrict__ W0, const float* __restrict__ b0,
    const float* __restrict__ x0, float* __restrict__ y0,
    const float* __restrict__ W1, const float* __restrict__ b1,
    const float* __restrict__ x1, float* __restrict__ y1,
    int ldx, int ldy, int K, float* zero_target)
{
    if (zero_target && blockIdx.x == 0 && blockIdx.y == 0 && threadIdx.x == 0) {
        zero_target[0] = 0.0f;
        zero_target[1] = 0.0f;
        ((unsigned int*)zero_target)[2] = 0u;
    }
    const float* W = W0; const float* bias = b0;
    const float* x = x0; float* y = y0;
    if (blockIdx.y == 1) { W = W1; bias = b1; x = x1; y = y1; }

    const int lane = threadIdx.x & 63;
    const int wv   = threadIdx.x >> 6;
    const int o    = (blockIdx.x << 2) + wv;   // gridDim.x = C/4 = 128

    float acc[BB];
    #pragma unroll
    for (int b = 0; b < BB; ++b) acc[b] = 0.0f;

    const float* Wr = W + (size_t)o * K;
    for (int t = lane; t < K; t += 64) {
        float w = Wr[t];
        #pragma unroll
        for (int b = 0; b < BB; ++b)
            acc[b] += w * x[b * ldx + t];
    }
    #pragma unroll
    for (int off = 32; off > 0; off >>= 1) {
        #pragma unroll
        for (int b = 0; b < BB; ++b)
            acc[b] += __shfl_xor(acc[b], off, 64);
    }
    if (lane == 0) {
        float bs = bias[o];
        #pragma unroll
        for (int b = 0; b < BB; ++b)
            y[b * ldy + o] = acc[b] + bs;
    }
}

// Gate stage: pre[b,o] = gate_w[o,:1024] . rd[b,:1024] + gate_b[o]
// Then BatchNorm over batch (spatially-constant => mean/var over the 8 batch
// values exactly equals the reference's mean/var over (B,H,W)), sigmoid gate,
// and fused value fv[b,o] = g*r + (1-g)*d. One wave per o holds all 8 batches.
__global__ __launch_bounds__(256) void k_gate(
    const float* __restrict__ gw, const float* __restrict__ gb,
    const float* __restrict__ rd,           // (B, 1024): [r | d] per batch
    const float* __restrict__ bng, const float* __restrict__ bnb,
    float* __restrict__ fv)                 // (B, 512)
{
    const int lane = threadIdx.x & 63;
    const int wv   = threadIdx.x >> 6;
    const int o    = (blockIdx.x << 2) + wv;   // gridDim.x = 128

    float acc[BB];
    #pragma unroll
    for (int b = 0; b < BB; ++b) acc[b] = 0.0f;

    const float* Wr = gw + (size_t)o * 1024;
    for (int t = lane; t < 1024; t += 64) {
        float w = Wr[t];
        #pragma unroll
        for (int b = 0; b < BB; ++b)
            acc[b] += w * rd[b * 1024 + t];
    }
    #pragma unroll
    for (int off = 32; off > 0; off >>= 1) {
        #pragma unroll
        for (int b = 0; b < BB; ++b)
            acc[b] += __shfl_xor(acc[b], off, 64);
    }
    if (lane == 0) {
        float bsv = gb[o];
        float pre[BB];
        float mean = 0.0f;
        #pragma unroll
        for (int b = 0; b < BB; ++b) { pre[b] = acc[b] + bsv; mean += pre[b]; }
        mean *= 0.125f;
        float var = 0.0f;
        #pragma unroll
        for (int b = 0; b < BB; ++b) { float dv = pre[b] - mean; var += dv * dv; }
        var *= 0.125f;
        float inv = rsqrtf(var + 1e-5f);
        float g = bng[o], bb2 = bnb[o];
        #pragma unroll
        for (int b = 0; b < BB; ++b) {
            float xh = (pre[b] - mean) * inv;
            float z  = g * xh + bb2;
            float gt = 1.0f / (1.0f + expf(-z));
            float rv = rd[b * 1024 + o];
            float dv = rd[b * 1024 + 512 + o];
            fv[b * CC + o] = gt * rv + (1.0f - gt) * dv;
        }
    }
}

// Big kernel: broadcast fused value over (H,W), compute both loss reductions.
// Vectorized float4; block reduce; device atomics; last block finalizes the
// two scalar outputs.
__global__ __launch_bounds__(256) void k_fuse(
    const float4* __restrict__ rgb, const float4* __restrict__ dep,
    const float* __restrict__ fv, float4* __restrict__ out,
    float* __restrict__ accs,          // [0]=sum_sq [1]=sum_abs [2]=counter(u32)
    float* __restrict__ out_sc)        // d_out + TOTAL (2 scalars)
{
    const int N4 = TOTAL / 4;          // 4194304
    const int stride = gridDim.x * blockDim.x;
    float ssq = 0.0f, sab = 0.0f;
    for (int j = blockIdx.x * blockDim.x + threadIdx.x; j < N4; j += stride) {
        float4 a = rgb[j];
        float4 b = dep[j];
        float f = fv[j >> 10];         // (4j)/4096 = b*512 + c
        out[j] = make_float4(f, f, f, f);
        float d0 = a.x - b.x, d1 = a.y - b.y, d2 = a.z - b.z, d3 = a.w - b.w;
        ssq += d0 * d0 + d1 * d1 + d2 * d2 + d3 * d3;
        sab += fabsf(d0) + fabsf(d1) + fabsf(d2) + fabsf(d3);
    }
    #pragma unroll
    for (int off = 32; off > 0; off >>= 1) {
        ssq += __shfl_xor(ssq, off, 64);
        sab += __shfl_xor(sab, off, 64);
    }
    __shared__ float ls[8];
    const int lane = threadIdx.x & 63;
    const int wv   = threadIdx.x >> 6;
    if (lane == 0) { ls[wv] = ssq; ls[4 + wv] = sab; }
    __syncthreads();
    if (threadIdx.x == 0) {
        float bsq = ls[0] + ls[1] + ls[2] + ls[3];
        float bab = ls[4] + ls[5] + ls[6] + ls[7];
        atomicAdd(&accs[0], bsq);
        atomicAdd(&accs[1], bab);
        __threadfence();
        unsigned int prev = atomicAdd((unsigned int*)&accs[2], 1u);
        if (prev == gridDim.x - 1) {
            float tsq = atomicAdd(&accs[0], 0.0f);
            float tab = atomicAdd(&accs[1], 0.0f);
            const float invN = 1.0f / (float)TOTAL;
            out_sc[0] = tsq * invN;
            out_sc[1] = tab * invN;
        }
    }
}

extern "C" void kernel_launch(void* const* d_in, const int* in_sizes, int n_in,
                              void* d_out, int out_size, void* d_ws, size_t ws_size,
                              hipStream_t stream) {
    const float* rgb   = (const float*)d_in[0];
    const float* dep   = (const float*)d_in[1];
    const float* text  = (const float*)d_in[2];
    const float* tp_w  = (const float*)d_in[3];
    const float* tp_b  = (const float*)d_in[4];
    const float* rwqkv = (const float*)d_in[5];
    const float* rbqkv = (const float*)d_in[6];
    const float* rwo   = (const float*)d_in[7];
    const float* rbo   = (const float*)d_in[8];
    const float* dwqkv = (const float*)d_in[9];
    const float* dbqkv = (const float*)d_in[10];
    const float* dwo   = (const float*)d_in[11];
    const float* dbo   = (const float*)d_in[12];
    const float* gw    = (const float*)d_in[13];
    const float* gb    = (const float*)d_in[14];
    const float* bng   = (const float*)d_in[15];
    const float* bnb   = (const float*)d_in[16];

    float* ws  = (float*)d_ws;
    float* tp  = ws;              // 4096: text_proj (B,512)
    float* vr  = ws + 4096;       // 4096: v_rgb (B,512)
    float* vd  = ws + 8192;       // 4096: v_dep (B,512)
    float* rd  = ws + 12288;      // 8192: [r|d] (B,1024)
    float* fv  = ws + 20480;      // 4096: fused value (B,512)
    float* accs = ws + 24576;     // 3: sum_sq, sum_abs, counter

    float* outf = (float*)d_out;

    // Stage 1: tp = text @ tp_w.T + tp_b     (also zeroes loss accumulators)
    k_mv<<<dim3(CC / 4, 1), 256, 0, stream>>>(
        tp_w, tp_b, text, tp, tp_w, tp_b, text, tp, 512, CC, 512, accs);

    // Stage 2: v = tp @ Wv.T + bv  (Wv = Wqkv rows [2C,3C)) for rgb & dep
    k_mv<<<dim3(CC / 4, 2), 256, 0, stream>>>(
        rwqkv + 1024 * 512, rbqkv + 1024, tp, vr,
        dwqkv + 1024 * 512, dbqkv + 1024, tp, vd, CC, CC, CC, nullptr);

    // Stage 3: r = vr @ Wo.T + bo -> rd[:, :512]; d -> rd[:, 512:]
    k_mv<<<dim3(CC / 4, 2), 256, 0, stream>>>(
        rwo, rbo, vr, rd,
        dwo, dbo, vd, rd + 512, CC, 1024, CC, nullptr);

    // Stage 4: pre = rd @ gate_w.T + gate_b; BN over batch; sigmoid; fuse value
    k_gate<<<CC / 4, 256, 0, stream>>>(gw, gb, rd, bng, bnb, fv);

    // Stage 5: broadcast fused over (H,W) + both losses (+ scalar finalize)
    k_fuse<<<2048, 256, 0, stream>>>(
        (const float4*)rgb, (const float4*)dep, fv, (float4*)outf,
        accs, outf + TOTAL);
}

// Round 3
// 229.956 us; speedup vs baseline: 1.4841x; 1.4841x over previous
//
#include <hip/hip_runtime.h>
#include <hip/hip_bf16.h>
#include <math.h>

// Problem constants (from reference):
//   B=8, C=512, H=W=64 -> HW=4096, L=HW, Td=512, N_HEADS=8 (irrelevant: KV len = 1)
// KEY INSIGHT: kv sequence length is 1 -> softmax over singleton axis == 1.0
// -> attention output == v broadcast over all L positions -> rgb_t/dep_t are
// per-(b,c) constants; Q projection and the big GEMMs are dead code. Only the
// two losses read the big tensors, and fused is a per-(b,c) value broadcast.
//
// R1 lesson: 2048 blocks x 3 same-cache-line device atomics + __threadfence
// serialized ~150us across XCDs. Replaced with per-block partials (plain
// stores) + a 1-block finalize kernel. No atomics anywhere now.
// R2 lesson: __builtin_nontemporal_* needs a clang ext_vector type, not HIP's
// struct float4.

#define BB 8
#define CC 512
#define HWSZ 4096
#define TOTAL (BB * CC * HWSZ)   // 16777216
#define FUSE_BLOCKS 1024

typedef float f32x4 __attribute__((ext_vector_type(4)));

// Generic batched mat-vec: y[b, o] = W[o, :K] . x[b, :K] + bias[o]
// One wave (64 lanes) per output o, accumulating all 8 batches at once.
// gridDim.y selects parameter set 0 or 1 (pairs rgb/dep stages in 1 launch).
__global__ __launch_bounds__(256) void k_mv(
    const float* __restrict__ W0, const float* __restrict__ b0,
    const float* __restrict__ x0, float* __restrict__ y0,
    const float* __restrict__ W1, const float* __restrict__ b1,
    const float* __restrict__ x1, float* __restrict__ y1,
    int ldx, int ldy, int K)
{
    const float* W = W0; const float* bias = b0;
    const float* x = x0; float* y = y0;
    if (blockIdx.y == 1) { W = W1; bias = b1; x = x1; y = y1; }

    const int lane = threadIdx.x & 63;
    const int wv   = threadIdx.x >> 6;
    const int o    = (blockIdx.x << 2) + wv;   // gridDim.x = C/4 = 128

    float acc[BB];
    #pragma unroll
    for (int b = 0; b < BB; ++b) acc[b] = 0.0f;

    const float* Wr = W + (size_t)o * K;
    for (int t = lane; t < K; t += 64) {
        float w = Wr[t];
        #pragma unroll
        for (int b = 0; b < BB; ++b)
            acc[b] += w * x[b * ldx + t];
    }
    #pragma unroll
    for (int off = 32; off > 0; off >>= 1) {
        #pragma unroll
        for (int b = 0; b < BB; ++b)
            acc[b] += __shfl_xor(acc[b], off, 64);
    }
    if (lane == 0) {
        float bs = bias[o];
        #pragma unroll
        for (int b = 0; b < BB; ++b)
            y[b * ldy + o] = acc[b] + bs;
    }
}

// Gate stage: pre[b,o] = gate_w[o,:1024] . rd[b,:1024] + gate_b[o]
// BN over batch (spatially-constant => stats over the 8 batch values equal
// the reference's stats over (B,H,W)), sigmoid gate, fused value per (b,o).
__global__ __launch_bounds__(256) void k_gate(
    const float* __restrict__ gw, const float* __restrict__ gb,
    const float* __restrict__ rd,           // (B, 1024): [r | d] per batch
    const float* __restrict__ bng, const float* __restrict__ bnb,
    float* __restrict__ fv)                 // (B, 512)
{
    const int lane = threadIdx.x & 63;
    const int wv   = threadIdx.x >> 6;
    const int o    = (blockIdx.x << 2) + wv;   // gridDim.x = 128

    float acc[BB];
    #pragma unroll
    for (int b = 0; b < BB; ++b) acc[b] = 0.0f;

    const float* Wr = gw + (size_t)o * 1024;
    for (int t = lane; t < 1024; t += 64) {
        float w = Wr[t];
        #pragma unroll
        for (int b = 0; b < BB; ++b)
            acc[b] += w * rd[b * 1024 + t];
    }
    #pragma unroll
    for (int off = 32; off > 0; off >>= 1) {
        #pragma unroll
        for (int b = 0; b < BB; ++b)
            acc[b] += __shfl_xor(acc[b], off, 64);
    }
    if (lane == 0) {
        float bsv = gb[o];
        float pre[BB];
        float mean = 0.0f;
        #pragma unroll
        for (int b = 0; b < BB; ++b) { pre[b] = acc[b] + bsv; mean += pre[b]; }
        mean *= 0.125f;
        float var = 0.0f;
        #pragma unroll
        for (int b = 0; b < BB; ++b) { float dv = pre[b] - mean; var += dv * dv; }
        var *= 0.125f;
        float inv = rsqrtf(var + 1e-5f);
        float g = bng[o], bb2 = bnb[o];
        #pragma unroll
        for (int b = 0; b < BB; ++b) {
            float xh = (pre[b] - mean) * inv;
            float z  = g * xh + bb2;
            float gt = 1.0f / (1.0f + expf(-z));
            float rv = rd[b * 1024 + o];
            float dv = rd[b * 1024 + 512 + o];
            fv[b * CC + o] = gt * rv + (1.0f - gt) * dv;
        }
    }
}

// Big streaming kernel: broadcast fused value over (H,W), accumulate both
// loss partials per block into private workspace slots (NO atomics).
__global__ __launch_bounds__(256) void k_fuse(
    const f32x4* __restrict__ rgb, const f32x4* __restrict__ dep,
    const float* __restrict__ fv, f32x4* __restrict__ out,
    float* __restrict__ partials)      // [FUSE_BLOCKS] ssq | [FUSE_BLOCKS] sab
{
    const int N4 = TOTAL / 4;          // 4194304
    const int stride = gridDim.x * blockDim.x;
    float ssq = 0.0f, sab = 0.0f;
    for (int j = blockIdx.x * blockDim.x + threadIdx.x; j < N4; j += stride) {
        f32x4 a = __builtin_nontemporal_load(&rgb[j]);
        f32x4 b = __builtin_nontemporal_load(&dep[j]);
        float f = fv[j >> 10];         // (4j)/4096 = b*512 + c
        f32x4 fvia = {f, f, f, f};
        __builtin_nontemporal_store(fvia, &out[j]);
        float d0 = a.x - b.x, d1 = a.y - b.y, d2 = a.z - b.z, d3 = a.w - b.w;
        ssq += d0 * d0 + d1 * d1 + d2 * d2 + d3 * d3;
        sab += fabsf(d0) + fabsf(d1) + fabsf(d2) + fabsf(d3);
    }
    #pragma unroll
    for (int off = 32; off > 0; off >>= 1) {
        ssq += __shfl_xor(ssq, off, 64);
        sab += __shfl_xor(sab, off, 64);
    }
    __shared__ float ls[8];
    const int lane = threadIdx.x & 63;
    const int wv   = threadIdx.x >> 6;
    if (lane == 0) { ls[wv] = ssq; ls[4 + wv] = sab; }
    __syncthreads();
    if (threadIdx.x == 0) {
        partials[blockIdx.x]               = ls[0] + ls[1] + ls[2] + ls[3];
        partials[FUSE_BLOCKS + blockIdx.x] = ls[4] + ls[5] + ls[6] + ls[7];
    }
}

// Single-block finalize: reduce FUSE_BLOCKS partials for each loss.
__global__ __launch_bounds__(256) void k_final(
    const float* __restrict__ partials, float* __restrict__ out_sc)
{
    float ssq = 0.0f, sab = 0.0f;
    for (int i = threadIdx.x; i < FUSE_BLOCKS; i += 256) {
        ssq += partials[i];
        sab += partials[FUSE_BLOCKS + i];
    }
    #pragma unroll
    for (int off = 32; off > 0; off >>= 1) {
        ssq += __shfl_xor(ssq, off, 64);
        sab += __shfl_xor(sab, off, 64);
    }
    __shared__ float ls[8];
    const int lane = threadIdx.x & 63;
    const int wv   = threadIdx.x >> 6;
    if (lane == 0) { ls[wv] = ssq; ls[4 + wv] = sab; }
    __syncthreads();
    if (threadIdx.x == 0) {
        const float invN = 1.0f / (float)TOTAL;
        out_sc[0] = (ls[0] + ls[1] + ls[2] + ls[3]) * invN;
        out_sc[1] = (ls[4] + ls[5] + ls[6] + ls[7]) * invN;
    }
}

extern "C" void kernel_launch(void* const* d_in, const int* in_sizes, int n_in,
                              void* d_out, int out_size, void* d_ws, size_t ws_size,
                              hipStream_t stream) {
    const float* rgb   = (const float*)d_in[0];
    const float* dep   = (const float*)d_in[1];
    const float* text  = (const float*)d_in[2];
    const float* tp_w  = (const float*)d_in[3];
    const float* tp_b  = (const float*)d_in[4];
    const float* rwqkv = (const float*)d_in[5];
    const float* rbqkv = (const float*)d_in[6];
    const float* rwo   = (const float*)d_in[7];
    const float* rbo   = (const float*)d_in[8];
    const float* dwqkv = (const float*)d_in[9];
    const float* dbqkv = (const float*)d_in[10];
    const float* dwo   = (const float*)d_in[11];
    const float* dbo   = (const float*)d_in[12];
    const float* gw    = (const float*)d_in[13];
    const float* gb    = (const float*)d_in[14];
    const float* bng   = (const float*)d_in[15];
    const float* bnb   = (const float*)d_in[16];

    float* ws  = (float*)d_ws;
    float* tp  = ws;              // 4096: text_proj (B,512)
    float* vr  = ws + 4096;       // 4096: v_rgb (B,512)
    float* vd  = ws + 8192;       // 4096: v_dep (B,512)
    float* rd  = ws + 12288;      // 8192: [r|d] (B,1024)
    float* fv  = ws + 20480;      // 4096: fused value (B,512)
    float* partials = ws + 24576; // 2*FUSE_BLOCKS

    float* outf = (float*)d_out;

    // Stage 1: tp = text @ tp_w.T + tp_b
    k_mv<<<dim3(CC / 4, 1), 256, 0, stream>>>(
        tp_w, tp_b, text, tp, tp_w, tp_b, text, tp, 512, CC, 512);

    // Stage 2: v = tp @ Wv.T + bv  (Wv = Wqkv rows [2C,3C)) for rgb & dep
    k_mv<<<dim3(CC / 4, 2), 256, 0, stream>>>(
        rwqkv + 1024 * 512, rbqkv + 1024, tp, vr,
        dwqkv + 1024 * 512, dbqkv + 1024, tp, vd, CC, CC, CC);

    // Stage 3: r = vr @ Wo.T + bo -> rd[:, :512]; d -> rd[:, 512:]
    k_mv<<<dim3(CC / 4, 2), 256, 0, stream>>>(
        rwo, rbo, vr, rd,
        dwo, dbo, vd, rd + 512, CC, 1024, CC);

    // Stage 4: pre = rd @ gate_w.T + gate_b; BN over batch; sigmoid; fuse value
    k_gate<<<CC / 4, 256, 0, stream>>>(gw, gb, rd, bng, bnb, fv);

    // Stage 5: broadcast fused over (H,W) + loss partials (no atomics)
    k_fuse<<<FUSE_BLOCKS, 256, 0, stream>>>(
        (const f32x4*)rgb, (const f32x4*)dep, fv, (f32x4*)outf, partials);

    // Stage 6: reduce partials -> two scalar outputs
    k_final<<<1, 256, 0, stream>>>(partials, outf + TOTAL);
}